// Round 5
// baseline (406.799 us; speedup 1.0000x reference)
//
#include <hip/hip_runtime.h>
#include <hip/hip_fp16.h>
#include <math.h>

#define HDIM   256
#define QLEN   64
#define NNUM   8
#define NOPS   9
#define NCOLS  16
#define TSTEPS 4

// op indices: SUM=0 COUNT=1 DIFF=2 GREATER=3 LESSER=4 AND=5 OR=6 ASSIGN=7 RESET=8

// ---- workspace layout (float offsets) ----
#define WS_LPIV 0
#define WS_GPIV 1
#define WS_ACOL 2            // [4][16]
#define WS_AOP  66           // [4][9]
#define WS_Q    112          // [256] final question RNN state q
#define WS_PQO  368          // [256] W_op[:, :256] @ q
#define WS_PQC  624          // [256] W_col[:, :256] @ q
#define WS_HS   880          // [8][256] hidden states at left_word_indices
#define WS_XP   2928         // [64][256] xproj
#define WS_AH   19312        // [256][9]  W_hist[:, :256] @ op_emb.T
#define WS_BH   21616        // [256][16] W_hist[:, 256:512] @ col_emb.T
#define WS_WH16 25712        // Wh as f16, MFMA-fragment order (32768 halfs = 16384 f)
#define WS_M16  42096        // 3x 256x256 f16 (h-side of W_op/W_col/W_hist): 98304 floats
#define WS_PART 140400       // [NBLK_C][8] block partials (D0..3, N0..3)
#define NBLK_C  2048

typedef _Float16 f16x8 __attribute__((ext_vector_type(8)));
typedef _Float16 f16x4 __attribute__((ext_vector_type(4)));
typedef float    f32x4 __attribute__((ext_vector_type(4)));
typedef float    f32x4u __attribute__((ext_vector_type(4), aligned(4)));

__device__ __forceinline__ float fast_tanh(float x) {
    return 1.0f - 2.0f / (__expf(2.0f * x) + 1.0f);
}

// ============================================================================
// Kernel A: parallel precompute.
//  gid ranges:
//   [0, 16384)              xproj[t][j] = emb[q[t]] . Wx[j,:]
//   [16384, 18688)          AH[j][o]  = W_hist[j,0:256] . op_emb[o,:]
//   [18688, 22784)          BH[j][c]  = W_hist[j,256:512] . col_emb[c,:]
//   [22784, 39168)          Wh -> f16 fragment-order pack (dwords)
//   [39168, 137472)         W_op/W_col/W_hist h-side halves -> f16 pack
//                           (32768 dwords = 65536 halfs per matrix)
// ============================================================================
__global__ void precompute_kernel(const int* __restrict__ q,
                                  const float* __restrict__ emb,
                                  const float* __restrict__ Wx,
                                  const float* __restrict__ Wh,
                                  const float* __restrict__ W_op,
                                  const float* __restrict__ W_col,
                                  const float* __restrict__ W_hist,
                                  const float* __restrict__ op_emb,
                                  const float* __restrict__ col_emb,
                                  float* __restrict__ ws) {
    int gid = blockIdx.x * 256 + threadIdx.x;
    if (gid < QLEN * HDIM) {
        int t = gid >> 8, j = gid & 255;
        const float4* x4 = (const float4*)(emb + (size_t)q[t] * HDIM);
        const float4* w4 = (const float4*)(Wx + (size_t)j * HDIM);
        float s = 0.f;
        for (int k = 0; k < HDIM / 4; k++) {
            float4 a = x4[k], b = w4[k];
            s += a.x * b.x + a.y * b.y + a.z * b.z + a.w * b.w;
        }
        ws[WS_XP + t * HDIM + j] = s;
    } else if (gid < QLEN * HDIM + HDIM * NOPS) {
        int idx = gid - QLEN * HDIM;
        int j = idx / NOPS, o = idx % NOPS;
        const float4* w4 = (const float4*)(W_hist + (size_t)j * (3 * HDIM));
        const float4* e4 = (const float4*)(op_emb + (size_t)o * HDIM);
        float s = 0.f;
        for (int k = 0; k < HDIM / 4; k++) {
            float4 a = w4[k], b = e4[k];
            s += a.x * b.x + a.y * b.y + a.z * b.z + a.w * b.w;
        }
        ws[WS_AH + idx] = s;
    } else if (gid < QLEN * HDIM + HDIM * NOPS + HDIM * NCOLS) {
        int idx = gid - QLEN * HDIM - HDIM * NOPS;
        int j = idx / NCOLS, c = idx % NCOLS;
        const float4* w4 = (const float4*)(W_hist + (size_t)j * (3 * HDIM) + HDIM);
        const float4* e4 = (const float4*)(col_emb + (size_t)c * HDIM);
        float s = 0.f;
        for (int k = 0; k < HDIM / 4; k++) {
            float4 a = w4[k], b = e4[k];
            s += a.x * b.x + a.y * b.y + a.z * b.z + a.w * b.w;
        }
        ws[WS_BH + idx] = s;
    } else if (gid < 22784 + 16384) {
        // Wh f16 pack: half-index = (((w16*8+kk)*4+quad)*16+qr)*8 + e,
        // value = Wh[16*w16+qr][kk*32 + quad*8 + e]
        int did = gid - 22784;
        int hidx = did * 2;
        int e = hidx & 7, qr = (hidx >> 3) & 15, quad = (hidx >> 7) & 3;
        int kk = (hidx >> 9) & 7, w = hidx >> 12;
        const float* src = Wh + (size_t)(16 * w + qr) * HDIM + kk * 32 + quad * 8 + e;
        float2 v = *(const float2*)src;
        ((__half2*)(ws + WS_WH16))[did] = __floats2half2_rn(v.x, v.y);
    } else if (gid < 22784 + 16384 + 98304) {
        // M16 pack: mat m = did>>15 (32768 dwords = 65536 halfs per mat),
        // within-mat half-index = ((i)*256 + j)*8 + e  (i in [0,32)),
        // value = W_m[j][off_m + i*8 + e]
        int did = gid - (22784 + 16384);
        int mat = did >> 15;
        int hidx = (did & 32767) * 2;
        int e = hidx & 7, j = (hidx >> 3) & 255, i = hidx >> 11;
        const float* src;
        if (mat == 0)      src = W_op   + (size_t)j * (2 * HDIM) + HDIM     + i * 8 + e;
        else if (mat == 1) src = W_col  + (size_t)j * (2 * HDIM) + HDIM     + i * 8 + e;
        else               src = W_hist + (size_t)j * (3 * HDIM) + 2 * HDIM + i * 8 + e;
        float2 v = *(const float2*)src;
        ((__half2*)(ws + WS_M16))[did] = __floats2half2_rn(v.x, v.y);
    }
}

// ============================================================================
// Kernel B1: single block, 256 threads (4 waves) — question RNN.
// Wave w owns rows [64w, 64w+64) as 4 MFMA row-tiles; the 8 B-fragments are
// loaded ONCE per lane per step and reused across all 4 tiles (4x fewer LDS
// instructions than the 16-wave version). XP staged in LDS; the K-loop does
// no global memory ops, so barriers drain only lgkmcnt.
// ============================================================================
__global__ __launch_bounds__(256, 1) void rnn_kernel(
        float* __restrict__ ws,
        const int* __restrict__ lwi) {
    __shared__ float xpL[QLEN * HDIM];      // 64 KB
    __shared__ _Float16 hF[2][HDIM];
    __shared__ float hsL[NNUM * HDIM];      // 8 KB
    __shared__ float hF32[HDIM];
    __shared__ int lwi_s[NNUM];

    const int tid = threadIdx.x;
    const int wave = tid >> 6, lane = tid & 63;
    const int quad = lane >> 4, qr = lane & 15;

    // stage xproj to LDS: 16384 floats, 16 float4s per thread, coalesced
    #pragma unroll
    for (int i = 0; i < 16; i++) {
        int idx = (i * 256 + tid) * 4;
        *(float4*)(xpL + idx) = *(const float4*)(ws + WS_XP + idx);
    }
    // A fragments: 4 row-tiles x 8 k-blocks (pre-packed f16, coalesced)
    const _Float16* wsh = (const _Float16*)(ws + WS_WH16);
    f16x8 aW[4][8];
    #pragma unroll
    for (int r = 0; r < 4; r++)
        #pragma unroll
        for (int kk = 0; kk < 8; kk++)
            aW[r][kk] = *(const f16x8*)(wsh + ((size_t)(((wave * 4 + r) * 8 + kk) * 64 + lane)) * 8);

    if (tid < NNUM) lwi_s[tid] = lwi[tid];
    hF[0][tid] = (_Float16)0.f;
    __syncthreads();

    for (int s = 0; s < QLEN; s++) {
        const _Float16* hb = hF[s & 1];
        f16x8 bfrag[8];
        #pragma unroll
        for (int kk = 0; kk < 8; kk++)
            bfrag[kk] = *(const f16x8*)(hb + kk * 32 + quad * 8);   // broadcast read
        f32x4 acc[4];
        #pragma unroll
        for (int r = 0; r < 4; r++) acc[r] = (f32x4){0.f, 0.f, 0.f, 0.f};
        #pragma unroll
        for (int kk = 0; kk < 8; kk++)
            #pragma unroll
            for (int r = 0; r < 4; r++)
                acc[r] = __builtin_amdgcn_mfma_f32_16x16x32_f16(aW[r][kk], bfrag[kk], acc[r], 0, 0, 0);
        #pragma unroll
        for (int r = 0; r < 4; r++) {
            int rb = 64 * wave + 16 * r + quad * 4;   // C/D rows this lane holds
            float4 xb = *(const float4*)(xpL + s * HDIM + rb);
            float h0 = fast_tanh(acc[r][0] + xb.x);
            float h1 = fast_tanh(acc[r][1] + xb.y);
            float h2 = fast_tanh(acc[r][2] + xb.z);
            float h3 = fast_tanh(acc[r][3] + xb.w);
            if (qr == 0) {
                f16x4 hv = {(_Float16)h0, (_Float16)h1, (_Float16)h2, (_Float16)h3};
                *(f16x4*)(&hF[(s + 1) & 1][rb]) = hv;
                if (s == QLEN - 1) *(float4*)(hF32 + rb) = make_float4(h0, h1, h2, h3);
                #pragma unroll
                for (int i = 0; i < NNUM; i++)
                    if (lwi_s[i] == s)   // uniform compare -> scalar branch
                        *(float4*)(hsL + i * HDIM + rb) = make_float4(h0, h1, h2, h3);
            }
        }
        __syncthreads();
    }
    // write back hs_sel and q
    #pragma unroll
    for (int i = 0; i < NNUM; i++) ws[WS_HS + i * HDIM + tid] = hsL[i * HDIM + tid];
    if (tid < 64) *(float4*)(ws + WS_Q + tid * 4) = *(const float4*)(hF32 + tid * 4);
}

// ============================================================================
// Kernel P2: parallel q-projections — pq_op[j] = W_op[j,:256].q,
// pq_col[j] = W_col[j,:256].q.  512 dots x 32 lanes = 64 blocks x 256.
// ============================================================================
__global__ void qproj_kernel(const float* __restrict__ W_op,
                             const float* __restrict__ W_col,
                             float* __restrict__ ws) {
    int gid = blockIdx.x * 256 + threadIdx.x;
    int dot = gid >> 5, l = gid & 31;
    int mat = dot >> 8, j = dot & 255;
    const float* w = (mat ? W_col : W_op) + (size_t)j * (2 * HDIM) + l * 8;
    const float* qv = ws + WS_Q + l * 8;
    float4 a0 = *(const float4*)w,        a1 = *(const float4*)(w + 4);
    float4 b0 = *(const float4*)qv,       b1 = *(const float4*)(qv + 4);
    float s = a0.x * b0.x + a0.y * b0.y + a0.z * b0.z + a0.w * b0.w
            + a1.x * b1.x + a1.y * b1.y + a1.z * b1.z + a1.w * b1.w;
    s += __shfl_xor(s, 1); s += __shfl_xor(s, 2); s += __shfl_xor(s, 4);
    s += __shfl_xor(s, 8); s += __shfl_xor(s, 16);
    if (l == 0) ws[(mat ? WS_PQC : WS_PQO) + j] = s;
}

// ============================================================================
// Kernel B2: single block, 256 threads — pivots + selector chain (T=4).
// ============================================================================
__global__ __launch_bounds__(256) void select_kernel(
        float* __restrict__ ws,
        const float* __restrict__ U,
        const int* __restrict__ nums,
        const float* __restrict__ op_emb,
        const float* __restrict__ col_emb) {
    __shared__ float zu[16];
    __shared__ float hH[HDIM];
    __shared__ float top_op[HDIM], top_col[HDIM], mh[HDIM];
    __shared__ float logits[32];
    __shared__ float aop_s[NOPS], acol_s[NCOLS];

    const int tid = threadIdx.x;

    // ---- pivots: 16 dots (i in [0,8), u in {0,1}), 16 lanes each ----
    {
        int g = tid >> 4, l = tid & 15;
        int i = g >> 1, u = g & 1;
        const float* z = ws + WS_HS + i * HDIM + l * 16;
        const float* uu = U + u * HDIM + l * 16;
        float s = 0.f;
        #pragma unroll
        for (int k = 0; k < 4; k++) {
            float4 a = *(const float4*)(z + k * 4), b = *(const float4*)(uu + k * 4);
            s += a.x * b.x + a.y * b.y + a.z * b.z + a.w * b.w;
        }
        s += __shfl_xor(s, 1); s += __shfl_xor(s, 2);
        s += __shfl_xor(s, 4); s += __shfl_xor(s, 8);
        if (l == 0) zu[g] = s;
    }
    if (tid < HDIM) hH[tid] = 0.f;
    __syncthreads();
    if (tid == 0) {
        #pragma unroll
        for (int u = 0; u < 2; u++) {
            float mx = -1e30f;
            for (int i = 0; i < NNUM; i++) mx = fmaxf(mx, zu[i * 2 + u]);
            float se = 0.f, pv = 0.f;
            for (int i = 0; i < NNUM; i++) {
                float e = __expf(zu[i * 2 + u] - mx);
                se += e;
                pv += e * (float)nums[i];
            }
            ws[u] = pv / se;
        }
    }
    __syncthreads();

    const _Float16* wsm = (const _Float16*)(ws + WS_M16);
    const float pqo = ws[WS_PQO + tid];
    const float pqc = ws[WS_PQC + tid];

    for (int t = 0; t < TSTEPS; t++) {
        float so = 0.f, sc = 0.f, sh = 0.f;
        #pragma unroll
        for (int i = 0; i < 32; i++) {
            float4 h0 = *(const float4*)(hH + i * 8);
            float4 h1 = *(const float4*)(hH + i * 8 + 4);
            f16x8 a = *(const f16x8*)(wsm + ((size_t)(0 * 32 + i) * 256 + tid) * 8);
            f16x8 b = *(const f16x8*)(wsm + ((size_t)(1 * 32 + i) * 256 + tid) * 8);
            f16x8 c = *(const f16x8*)(wsm + ((size_t)(2 * 32 + i) * 256 + tid) * 8);
            so += (float)a[0]*h0.x + (float)a[1]*h0.y + (float)a[2]*h0.z + (float)a[3]*h0.w
                + (float)a[4]*h1.x + (float)a[5]*h1.y + (float)a[6]*h1.z + (float)a[7]*h1.w;
            sc += (float)b[0]*h0.x + (float)b[1]*h0.y + (float)b[2]*h0.z + (float)b[3]*h0.w
                + (float)b[4]*h1.x + (float)b[5]*h1.y + (float)b[6]*h1.z + (float)b[7]*h1.w;
            sh += (float)c[0]*h0.x + (float)c[1]*h0.y + (float)c[2]*h0.z + (float)c[3]*h0.w
                + (float)c[4]*h1.x + (float)c[5]*h1.y + (float)c[6]*h1.z + (float)c[7]*h1.w;
        }
        top_op[tid]  = fast_tanh(pqo + so);
        top_col[tid] = fast_tanh(pqc + sc);
        mh[tid] = sh;
        __syncthreads();

        // logits: 25 dots of 256, 32 lanes each, 8 groups per pass
        #pragma unroll
        for (int d0 = 0; d0 < 32; d0 += 8) {
            int d = d0 + (tid >> 5), l = tid & 31;
            if (d < 25) {
                float s = 0.f;
                if (d < NOPS) {
                    const float* e = op_emb + (size_t)d * HDIM;
                    #pragma unroll
                    for (int m = 0; m < 8; m++) s += e[l * 8 + m] * top_op[l * 8 + m];
                } else {
                    const float* e = col_emb + (size_t)(d - NOPS) * HDIM;
                    #pragma unroll
                    for (int m = 0; m < 8; m++) s += e[l * 8 + m] * top_col[l * 8 + m];
                }
                s += __shfl_xor(s, 1); s += __shfl_xor(s, 2); s += __shfl_xor(s, 4);
                s += __shfl_xor(s, 8); s += __shfl_xor(s, 16);
                if (l == 0) logits[d] = s;
            }
        }
        __syncthreads();
        if (tid == 0) {
            float mx = -1e30f;
            for (int o = 0; o < NOPS; o++) mx = fmaxf(mx, logits[o]);
            float se = 0.f, e[NOPS];
            for (int o = 0; o < NOPS; o++) { e[o] = __expf(logits[o] - mx); se += e[o]; }
            for (int o = 0; o < NOPS; o++) {
                float a = e[o] / se;
                aop_s[o] = a;
                ws[WS_AOP + t * NOPS + o] = a;
            }
        } else if (tid == 32) {
            float mx = -1e30f;
            for (int c = 0; c < NCOLS; c++) mx = fmaxf(mx, logits[NOPS + c]);
            float se = 0.f, e[NCOLS];
            for (int c = 0; c < NCOLS; c++) { e[c] = __expf(logits[NOPS + c] - mx); se += e[c]; }
            for (int c = 0; c < NCOLS; c++) {
                float a = e[c] / se;
                acol_s[c] = a;
                ws[WS_ACOL + t * NCOLS + c] = a;
            }
        }
        __syncthreads();
        // h_hist update (all 256 rows, one per thread)
        {
            float s = mh[tid];
            const float* ah = ws + WS_AH + tid * NOPS;
            #pragma unroll
            for (int o = 0; o < NOPS; o++) s += ah[o] * aop_s[o];
            const float* bh = ws + WS_BH + tid * NCOLS;
            #pragma unroll
            for (int c = 0; c < NCOLS; c++) s += bh[c] * acol_s[c];
            float hv = fast_tanh(s);
            __syncthreads();
            hH[tid] = hv;
        }
        __syncthreads();
    }
}

// ============================================================================
// Kernel C: fused table pass, 4 lanes per row (cq = tid&3 owns cols 4cq..4cq+3).
// Loads and stores are contiguous: address = const + tid*16B. Cross-lane
// sums via 2 shfl_xor. rs recursion duplicated in the 4 lanes (exact), block
// partials scaled by 0.25 to undo the duplication.
// ============================================================================
__global__ __launch_bounds__(256) void table_kernel(
        const float* __restrict__ table,
        const float* __restrict__ wsc,
        float* __restrict__ wspart,
        float* __restrict__ out,
        int rows) {
    const int tid = threadIdx.x;
    const int cq = tid & 3;
    const float lpiv = wsc[WS_LPIV];
    const float gpiv = wsc[WS_GPIV];
    float4 acol4[TSTEPS];
    float wg[TSTEPS], wl[TSTEPS], wand[TSTEPS], wor[TSTEPS], wrst[TSTEPS], wpass[TSTEPS];
    #pragma unroll
    for (int t = 0; t < TSTEPS; t++) {
        acol4[t] = make_float4(wsc[WS_ACOL + t * NCOLS + cq * 4 + 0],
                               wsc[WS_ACOL + t * NCOLS + cq * 4 + 1],
                               wsc[WS_ACOL + t * NCOLS + cq * 4 + 2],
                               wsc[WS_ACOL + t * NCOLS + cq * 4 + 3]);
        wg[t]   = wsc[WS_AOP + t * NOPS + 3];
        wl[t]   = wsc[WS_AOP + t * NOPS + 4];
        wand[t] = wsc[WS_AOP + t * NOPS + 5];
        wor[t]  = wsc[WS_AOP + t * NOPS + 6];
        wrst[t] = wsc[WS_AOP + t * NOPS + 8];
        wpass[t] = wsc[WS_AOP + t * NOPS + 0] + wsc[WS_AOP + t * NOPS + 1]
                 + wsc[WS_AOP + t * NOPS + 2] + wsc[WS_AOP + t * NOPS + 7];
    }
    const float wassign = wsc[WS_AOP + 3 * NOPS + 7];

    float dAcc[TSTEPS] = {0.f, 0.f, 0.f, 0.f};
    float nAcc[TSTEPS] = {0.f, 0.f, 0.f, 0.f};
    const long rowsL = rows;

    for (long r0 = (long)blockIdx.x * 64; r0 < rowsL; r0 += (long)NBLK_C * 64) {
        long row = r0 + (tid >> 2);
        bool valid = row < rowsL;
        float4 tv = valid ? *(const float4*)(table + row * NCOLS + cq * 4)
                          : make_float4(0.f, 0.f, 0.f, 0.f);
        float prs = tv.x + tv.y + tv.z + tv.w;
        float pg[4], pl[4];
        {
            float c0 = tv.x, c1 = tv.y, c2 = tv.z, c3 = tv.w;
            float sg0 = __builtin_amdgcn_rcpf(1.f + __expf(gpiv - c0));
            float sg1 = __builtin_amdgcn_rcpf(1.f + __expf(gpiv - c1));
            float sg2 = __builtin_amdgcn_rcpf(1.f + __expf(gpiv - c2));
            float sg3 = __builtin_amdgcn_rcpf(1.f + __expf(gpiv - c3));
            float sl0 = __builtin_amdgcn_rcpf(1.f + __expf(c0 - lpiv));
            float sl1 = __builtin_amdgcn_rcpf(1.f + __expf(c1 - lpiv));
            float sl2 = __builtin_amdgcn_rcpf(1.f + __expf(c2 - lpiv));
            float sl3 = __builtin_amdgcn_rcpf(1.f + __expf(c3 - lpiv));
            #pragma unroll
            for (int t = 0; t < TSTEPS; t++) {
                pg[t] = sg0 * acol4[t].x + sg1 * acol4[t].y + sg2 * acol4[t].z + sg3 * acol4[t].w;
                pl[t] = sl0 * acol4[t].x + sl1 * acol4[t].y + sl2 * acol4[t].z + sl3 * acol4[t].w;
            }
        }
        // reduce over the 4 lanes of this row (lanes differ in low 2 bits)
        prs += __shfl_xor(prs, 1); prs += __shfl_xor(prs, 2);
        #pragma unroll
        for (int t = 0; t < TSTEPS; t++) {
            pg[t] += __shfl_xor(pg[t], 1); pg[t] += __shfl_xor(pg[t], 2);
            pl[t] += __shfl_xor(pl[t], 1); pl[t] += __shfl_xor(pl[t], 2);
        }
        float rs1 = 1.f, rs2 = 1.f;
        float vf = valid ? 1.f : 0.f;
        #pragma unroll
        for (int i = 0; i < TSTEPS; i++) {
            dAcc[i] += vf * rs1 * prs;
            nAcc[i] += vf * rs1;
            float nrs = wg[i] * pg[i] + wl[i] * pl[i]
                      + wand[i] * fminf(rs1, rs2) + wor[i] * fmaxf(rs1, rs2)
                      + wrst[i] + wpass[i] * rs1;
            rs2 = rs1;
            rs1 = nrs;
        }
        if (valid) {
            float wa = wassign * rs1;   // rs^(4)
            f32x4u v = {wa * acol4[3].x, wa * acol4[3].y, wa * acol4[3].z, wa * acol4[3].w};
            *(f32x4u*)(out + 1 + row * NCOLS + cq * 4) = v;
        }
    }

    // block reduction of 8 partials (each row counted 4x -> scale 0.25)
    #pragma unroll
    for (int i = 0; i < TSTEPS; i++) {
        #pragma unroll
        for (int off = 32; off >= 1; off >>= 1) {
            dAcc[i] += __shfl_xor(dAcc[i], off);
            nAcc[i] += __shfl_xor(nAcc[i], off);
        }
    }
    __shared__ float redl[4][8];
    int wv = tid >> 6, ln = tid & 63;
    if (ln == 0) {
        #pragma unroll
        for (int i = 0; i < TSTEPS; i++) {
            redl[wv][i] = dAcc[i];
            redl[wv][4 + i] = nAcc[i];
        }
    }
    __syncthreads();
    if (tid < 8) {
        float s = redl[0][tid] + redl[1][tid] + redl[2][tid] + redl[3][tid];
        wspart[blockIdx.x * 8 + tid] = 0.25f * s;
    }
}

// ============================================================================
// Kernel D: reduce block partials, run the 4-step scalar recurrence
// ============================================================================
__global__ void finalize_kernel(const float* __restrict__ ws, float* __restrict__ out) {
    __shared__ float red[8];
    int a = threadIdx.x >> 5, l = threadIdx.x & 31;
    float s = 0.f;
    for (int b = l; b < NBLK_C; b += 32) s += ws[WS_PART + b * 8 + a];
    s += __shfl_xor(s, 1, 32); s += __shfl_xor(s, 2, 32); s += __shfl_xor(s, 4, 32);
    s += __shfl_xor(s, 8, 32); s += __shfl_xor(s, 16, 32);
    if (l == 0) red[a] = s;
    __syncthreads();
    if (threadIdx.x == 0) {
        float Dv[4] = {red[0], red[1], red[2], red[3]};
        float Nv[4] = {red[4], red[5], red[6], red[7]};
        const float* aop = ws + WS_AOP;
        float sc[5];
        sc[0] = 0.f;
        #pragma unroll
        for (int i = 0; i < 4; i++) {
            float s1 = sc[i];
            float s3 = sc[(i >= 2) ? (i - 2) : 0];
            sc[i + 1] = aop[i * NOPS + 0] * Dv[i] + aop[i * NOPS + 1] * Nv[i]
                      + aop[i * NOPS + 2] * (s3 - s1);
        }
        out[0] = sc[4];
    }
}

// ============================================================================
extern "C" void kernel_launch(void* const* d_in, const int* in_sizes, int n_in,
                              void* d_out, int out_size, void* d_ws, size_t ws_size,
                              hipStream_t stream) {
    const int*   q       = (const int*)d_in[0];
    const int*   nums    = (const int*)d_in[1];
    const int*   lwi     = (const int*)d_in[2];
    const float* table   = (const float*)d_in[3];
    const float* emb     = (const float*)d_in[4];
    const float* Wx      = (const float*)d_in[5];
    const float* Wh      = (const float*)d_in[6];
    const float* W_op    = (const float*)d_in[7];
    const float* op_emb  = (const float*)d_in[8];
    const float* W_col   = (const float*)d_in[9];
    const float* col_emb = (const float*)d_in[10];
    const float* W_hist  = (const float*)d_in[11];
    const float* U       = (const float*)d_in[12];
    float* out = (float*)d_out;
    float* ws  = (float*)d_ws;
    int rows = in_sizes[3] / NCOLS;

    const int pre_outputs = 137472;   // see precompute_kernel gid map
    precompute_kernel<<<(pre_outputs + 255) / 256, 256, 0, stream>>>(
        q, emb, Wx, Wh, W_op, W_col, W_hist, op_emb, col_emb, ws);
    rnn_kernel<<<1, 256, 0, stream>>>(ws, lwi);
    qproj_kernel<<<64, 256, 0, stream>>>(W_op, W_col, ws);
    select_kernel<<<1, 256, 0, stream>>>(ws, U, nums, op_emb, col_emb);
    table_kernel<<<NBLK_C, 256, 0, stream>>>(
        table, ws, ws + WS_PART, out, rows);
    finalize_kernel<<<1, 256, 0, stream>>>(ws, out);
}

// Round 6
// 305.633 us; speedup vs baseline: 1.3310x; 1.3310x over previous
//
#include <hip/hip_runtime.h>
#include <hip/hip_fp16.h>
#include <math.h>

#define HDIM   256
#define QLEN   64
#define NNUM   8
#define NOPS   9
#define NCOLS  16
#define TSTEPS 4

// op indices: SUM=0 COUNT=1 DIFF=2 GREATER=3 LESSER=4 AND=5 OR=6 ASSIGN=7 RESET=8

// ---- workspace layout (float offsets) ----
#define WS_LPIV 0
#define WS_GPIV 1
#define WS_ACOL 2            // [4][16]
#define WS_AOP  66           // [4][9]
#define WS_Q    112          // [256] final question RNN state q
#define WS_PQO  368          // [256] W_op[:, :256] @ q
#define WS_PQC  624          // [256] W_col[:, :256] @ q
#define WS_HS   880          // [8][256] hidden states at left_word_indices
#define WS_XP   2928         // [64][256] xproj
#define WS_AH   19312        // [256][9]  W_hist[:, :256] @ op_emb.T
#define WS_BH   21616        // [256][16] W_hist[:, 256:512] @ col_emb.T
#define WS_WH16 25712        // Wh as f16, MFMA-fragment order (32768 halfs = 16384 f)
#define WS_M16  42096        // 3x 256x256 f16 (h-side of W_op/W_col/W_hist): 98304 floats
#define WS_PART 140400       // [NBLK_C][8] block partials (D0..3, N0..3)
#define NBLK_C  2048

typedef _Float16 f16x8 __attribute__((ext_vector_type(8)));
typedef _Float16 f16x4 __attribute__((ext_vector_type(4)));
typedef float    f32x4 __attribute__((ext_vector_type(4)));
typedef float    f32x4u __attribute__((ext_vector_type(4), aligned(4)));

__device__ __forceinline__ float fast_tanh(float x) {
    return 1.0f - 2.0f / (__expf(2.0f * x) + 1.0f);
}

// ============================================================================
// Kernel A: parallel precompute.
//  gid ranges:
//   [0, 16384)              xproj[t][j] = emb[q[t]] . Wx[j,:]
//   [16384, 18688)          AH[j][o]  = W_hist[j,0:256] . op_emb[o,:]
//   [18688, 22784)          BH[j][c]  = W_hist[j,256:512] . col_emb[c,:]
//   [22784, 39168)          Wh -> f16 fragment-order pack (dwords)
//   [39168, 137472)         W_op/W_col/W_hist h-side halves -> f16 pack
//                           (32768 dwords = 65536 halfs per matrix)
// ============================================================================
__global__ void precompute_kernel(const int* __restrict__ q,
                                  const float* __restrict__ emb,
                                  const float* __restrict__ Wx,
                                  const float* __restrict__ Wh,
                                  const float* __restrict__ W_op,
                                  const float* __restrict__ W_col,
                                  const float* __restrict__ W_hist,
                                  const float* __restrict__ op_emb,
                                  const float* __restrict__ col_emb,
                                  float* __restrict__ ws) {
    int gid = blockIdx.x * 256 + threadIdx.x;
    if (gid < QLEN * HDIM) {
        int t = gid >> 8, j = gid & 255;
        const float4* x4 = (const float4*)(emb + (size_t)q[t] * HDIM);
        const float4* w4 = (const float4*)(Wx + (size_t)j * HDIM);
        float s = 0.f;
        for (int k = 0; k < HDIM / 4; k++) {
            float4 a = x4[k], b = w4[k];
            s += a.x * b.x + a.y * b.y + a.z * b.z + a.w * b.w;
        }
        ws[WS_XP + t * HDIM + j] = s;
    } else if (gid < QLEN * HDIM + HDIM * NOPS) {
        int idx = gid - QLEN * HDIM;
        int j = idx / NOPS, o = idx % NOPS;
        const float4* w4 = (const float4*)(W_hist + (size_t)j * (3 * HDIM));
        const float4* e4 = (const float4*)(op_emb + (size_t)o * HDIM);
        float s = 0.f;
        for (int k = 0; k < HDIM / 4; k++) {
            float4 a = w4[k], b = e4[k];
            s += a.x * b.x + a.y * b.y + a.z * b.z + a.w * b.w;
        }
        ws[WS_AH + idx] = s;
    } else if (gid < QLEN * HDIM + HDIM * NOPS + HDIM * NCOLS) {
        int idx = gid - QLEN * HDIM - HDIM * NOPS;
        int j = idx / NCOLS, c = idx % NCOLS;
        const float4* w4 = (const float4*)(W_hist + (size_t)j * (3 * HDIM) + HDIM);
        const float4* e4 = (const float4*)(col_emb + (size_t)c * HDIM);
        float s = 0.f;
        for (int k = 0; k < HDIM / 4; k++) {
            float4 a = w4[k], b = e4[k];
            s += a.x * b.x + a.y * b.y + a.z * b.z + a.w * b.w;
        }
        ws[WS_BH + idx] = s;
    } else if (gid < 22784 + 16384) {
        // Wh f16 pack: half-index = (((w16*8+kk)*4+quad)*16+qr)*8 + e,
        // value = Wh[16*w16+qr][kk*32 + quad*8 + e]
        int did = gid - 22784;
        int hidx = did * 2;
        int e = hidx & 7, qr = (hidx >> 3) & 15, quad = (hidx >> 7) & 3;
        int kk = (hidx >> 9) & 7, w = hidx >> 12;
        const float* src = Wh + (size_t)(16 * w + qr) * HDIM + kk * 32 + quad * 8 + e;
        float2 v = *(const float2*)src;
        ((__half2*)(ws + WS_WH16))[did] = __floats2half2_rn(v.x, v.y);
    } else if (gid < 22784 + 16384 + 98304) {
        // M16 pack: mat m = did>>15 (32768 dwords = 65536 halfs per mat),
        // within-mat half-index = ((i)*256 + j)*8 + e  (i in [0,32)),
        // value = W_m[j][off_m + i*8 + e]
        int did = gid - (22784 + 16384);
        int mat = did >> 15;
        int hidx = (did & 32767) * 2;
        int e = hidx & 7, j = (hidx >> 3) & 255, i = hidx >> 11;
        const float* src;
        if (mat == 0)      src = W_op   + (size_t)j * (2 * HDIM) + HDIM     + i * 8 + e;
        else if (mat == 1) src = W_col  + (size_t)j * (2 * HDIM) + HDIM     + i * 8 + e;
        else               src = W_hist + (size_t)j * (3 * HDIM) + 2 * HDIM + i * 8 + e;
        float2 v = *(const float2*)src;
        ((__half2*)(ws + WS_M16))[did] = __floats2half2_rn(v.x, v.y);
    }
}

// ============================================================================
// Kernel B1: single block, 1024 threads (16 waves) — question RNN.
// Wave w owns rows [16w,16w+16): ONE A-tile per wave (32 VGPRs — the layout
// the compiler provably keeps register-resident; 4-tile variants get their
// registers capped and re-materialize from L2 inside the loop, 2x slower).
// XP staged in LDS so the step loop has NO global memory ops (no vmcnt drain
// at the barrier). MFMA chain split into two 4-deep accumulators.
// ============================================================================
__global__ __launch_bounds__(1024) void rnn_kernel(
        float* __restrict__ ws,
        const int* __restrict__ lwi) {
    __shared__ float xpL[QLEN * HDIM];      // 64 KB
    __shared__ _Float16 hF[2][HDIM];
    __shared__ float hsL[NNUM * HDIM];      // 8 KB
    __shared__ float hF32[HDIM];
    __shared__ int lwi_s[NNUM];

    const int tid = threadIdx.x;
    const int wave = tid >> 6, lane = tid & 63;
    const int quad = lane >> 4, qr = lane & 15;

    // stage xproj to LDS: 16384 floats = 4096 float4s, 4 per thread, coalesced
    #pragma unroll
    for (int i = 0; i < 4; i++) {
        int idx = (i * 1024 + tid) * 4;
        *(float4*)(xpL + idx) = *(const float4*)(ws + WS_XP + idx);
    }
    // A fragments: pre-packed f16, per (wave,kk) the 64 lanes read 1 KB contiguous
    const _Float16* wsh = (const _Float16*)(ws + WS_WH16);
    f16x8 aW[8];
    #pragma unroll
    for (int kk = 0; kk < 8; kk++)
        aW[kk] = *(const f16x8*)(wsh + ((size_t)((wave * 8 + kk) * 64 + lane)) * 8);

    if (tid < NNUM) lwi_s[tid] = lwi[tid];
    if (tid < HDIM) hF[0][tid] = (_Float16)0.f;
    __syncthreads();

    const int rb = 16 * wave + quad * 4;   // C/D rows this lane holds
    for (int s = 0; s < QLEN; s++) {
        const _Float16* hb = hF[s & 1];
        f16x8 bfrag[8];
        #pragma unroll
        for (int kk = 0; kk < 8; kk++)
            bfrag[kk] = *(const f16x8*)(hb + kk * 32 + quad * 8);   // broadcast read
        f32x4 acc0 = {0.f, 0.f, 0.f, 0.f};
        f32x4 acc1 = {0.f, 0.f, 0.f, 0.f};
        #pragma unroll
        for (int kk = 0; kk < 4; kk++) {
            acc0 = __builtin_amdgcn_mfma_f32_16x16x32_f16(aW[kk],     bfrag[kk],     acc0, 0, 0, 0);
            acc1 = __builtin_amdgcn_mfma_f32_16x16x32_f16(aW[kk + 4], bfrag[kk + 4], acc1, 0, 0, 0);
        }
        float4 xb = *(const float4*)(xpL + s * HDIM + rb);
        float h0 = fast_tanh(acc0[0] + acc1[0] + xb.x);
        float h1 = fast_tanh(acc0[1] + acc1[1] + xb.y);
        float h2 = fast_tanh(acc0[2] + acc1[2] + xb.z);
        float h3 = fast_tanh(acc0[3] + acc1[3] + xb.w);
        if (qr == 0) {                       // one writer per quad
            f16x4 hv = {(_Float16)h0, (_Float16)h1, (_Float16)h2, (_Float16)h3};
            *(f16x4*)(&hF[(s + 1) & 1][rb]) = hv;
            if (s == QLEN - 1) *(float4*)(hF32 + rb) = make_float4(h0, h1, h2, h3);
            #pragma unroll
            for (int i = 0; i < NNUM; i++)
                if (lwi_s[i] == s)           // uniform compare -> scalar branch
                    *(float4*)(hsL + i * HDIM + rb) = make_float4(h0, h1, h2, h3);
        }
        __syncthreads();
    }
    // write back hs_sel and q
    for (int i = tid; i < NNUM * HDIM; i += 1024) ws[WS_HS + i] = hsL[i];
    if (tid < 64) *(float4*)(ws + WS_Q + tid * 4) = *(const float4*)(hF32 + tid * 4);
}

// ============================================================================
// Kernel P2: parallel q-projections — pq_op[j] = W_op[j,:256].q,
// pq_col[j] = W_col[j,:256].q.  512 dots x 32 lanes = 64 blocks x 256.
// ============================================================================
__global__ void qproj_kernel(const float* __restrict__ W_op,
                             const float* __restrict__ W_col,
                             float* __restrict__ ws) {
    int gid = blockIdx.x * 256 + threadIdx.x;
    int dot = gid >> 5, l = gid & 31;
    int mat = dot >> 8, j = dot & 255;
    const float* w = (mat ? W_col : W_op) + (size_t)j * (2 * HDIM) + l * 8;
    const float* qv = ws + WS_Q + l * 8;
    float4 a0 = *(const float4*)w,        a1 = *(const float4*)(w + 4);
    float4 b0 = *(const float4*)qv,       b1 = *(const float4*)(qv + 4);
    float s = a0.x * b0.x + a0.y * b0.y + a0.z * b0.z + a0.w * b0.w
            + a1.x * b1.x + a1.y * b1.y + a1.z * b1.z + a1.w * b1.w;
    s += __shfl_xor(s, 1); s += __shfl_xor(s, 2); s += __shfl_xor(s, 4);
    s += __shfl_xor(s, 8); s += __shfl_xor(s, 16);
    if (l == 0) ws[(mat ? WS_PQC : WS_PQO) + j] = s;
}

// ============================================================================
// Kernel B2: single block, 256 threads — pivots + selector chain (T=4).
// ============================================================================
__global__ __launch_bounds__(256) void select_kernel(
        float* __restrict__ ws,
        const float* __restrict__ U,
        const int* __restrict__ nums,
        const float* __restrict__ op_emb,
        const float* __restrict__ col_emb) {
    __shared__ float zu[16];
    __shared__ float hH[HDIM];
    __shared__ float top_op[HDIM], top_col[HDIM], mh[HDIM];
    __shared__ float logits[32];
    __shared__ float aop_s[NOPS], acol_s[NCOLS];

    const int tid = threadIdx.x;

    // ---- pivots: 16 dots (i in [0,8), u in {0,1}), 16 lanes each ----
    {
        int g = tid >> 4, l = tid & 15;
        int i = g >> 1, u = g & 1;
        const float* z = ws + WS_HS + i * HDIM + l * 16;
        const float* uu = U + u * HDIM + l * 16;
        float s = 0.f;
        #pragma unroll
        for (int k = 0; k < 4; k++) {
            float4 a = *(const float4*)(z + k * 4), b = *(const float4*)(uu + k * 4);
            s += a.x * b.x + a.y * b.y + a.z * b.z + a.w * b.w;
        }
        s += __shfl_xor(s, 1); s += __shfl_xor(s, 2);
        s += __shfl_xor(s, 4); s += __shfl_xor(s, 8);
        if (l == 0) zu[g] = s;
    }
    if (tid < HDIM) hH[tid] = 0.f;
    __syncthreads();
    if (tid == 0) {
        #pragma unroll
        for (int u = 0; u < 2; u++) {
            float mx = -1e30f;
            for (int i = 0; i < NNUM; i++) mx = fmaxf(mx, zu[i * 2 + u]);
            float se = 0.f, pv = 0.f;
            for (int i = 0; i < NNUM; i++) {
                float e = __expf(zu[i * 2 + u] - mx);
                se += e;
                pv += e * (float)nums[i];
            }
            ws[u] = pv / se;
        }
    }
    __syncthreads();

    const _Float16* wsm = (const _Float16*)(ws + WS_M16);
    const float pqo = ws[WS_PQO + tid];
    const float pqc = ws[WS_PQC + tid];

    for (int t = 0; t < TSTEPS; t++) {
        float so = 0.f, sc = 0.f, sh = 0.f;
        #pragma unroll
        for (int i = 0; i < 32; i++) {
            float4 h0 = *(const float4*)(hH + i * 8);
            float4 h1 = *(const float4*)(hH + i * 8 + 4);
            f16x8 a = *(const f16x8*)(wsm + ((size_t)(0 * 32 + i) * 256 + tid) * 8);
            f16x8 b = *(const f16x8*)(wsm + ((size_t)(1 * 32 + i) * 256 + tid) * 8);
            f16x8 c = *(const f16x8*)(wsm + ((size_t)(2 * 32 + i) * 256 + tid) * 8);
            so += (float)a[0]*h0.x + (float)a[1]*h0.y + (float)a[2]*h0.z + (float)a[3]*h0.w
                + (float)a[4]*h1.x + (float)a[5]*h1.y + (float)a[6]*h1.z + (float)a[7]*h1.w;
            sc += (float)b[0]*h0.x + (float)b[1]*h0.y + (float)b[2]*h0.z + (float)b[3]*h0.w
                + (float)b[4]*h1.x + (float)b[5]*h1.y + (float)b[6]*h1.z + (float)b[7]*h1.w;
            sh += (float)c[0]*h0.x + (float)c[1]*h0.y + (float)c[2]*h0.z + (float)c[3]*h0.w
                + (float)c[4]*h1.x + (float)c[5]*h1.y + (float)c[6]*h1.z + (float)c[7]*h1.w;
        }
        top_op[tid]  = fast_tanh(pqo + so);
        top_col[tid] = fast_tanh(pqc + sc);
        mh[tid] = sh;
        __syncthreads();

        // logits: 25 dots of 256, 32 lanes each, 8 groups per pass
        #pragma unroll
        for (int d0 = 0; d0 < 32; d0 += 8) {
            int d = d0 + (tid >> 5), l = tid & 31;
            if (d < 25) {
                float s = 0.f;
                if (d < NOPS) {
                    const float* e = op_emb + (size_t)d * HDIM;
                    #pragma unroll
                    for (int m = 0; m < 8; m++) s += e[l * 8 + m] * top_op[l * 8 + m];
                } else {
                    const float* e = col_emb + (size_t)(d - NOPS) * HDIM;
                    #pragma unroll
                    for (int m = 0; m < 8; m++) s += e[l * 8 + m] * top_col[l * 8 + m];
                }
                s += __shfl_xor(s, 1); s += __shfl_xor(s, 2); s += __shfl_xor(s, 4);
                s += __shfl_xor(s, 8); s += __shfl_xor(s, 16);
                if (l == 0) logits[d] = s;
            }
        }
        __syncthreads();
        if (tid == 0) {
            float mx = -1e30f;
            for (int o = 0; o < NOPS; o++) mx = fmaxf(mx, logits[o]);
            float se = 0.f, e[NOPS];
            for (int o = 0; o < NOPS; o++) { e[o] = __expf(logits[o] - mx); se += e[o]; }
            for (int o = 0; o < NOPS; o++) {
                float a = e[o] / se;
                aop_s[o] = a;
                ws[WS_AOP + t * NOPS + o] = a;
            }
        } else if (tid == 32) {
            float mx = -1e30f;
            for (int c = 0; c < NCOLS; c++) mx = fmaxf(mx, logits[NOPS + c]);
            float se = 0.f, e[NCOLS];
            for (int c = 0; c < NCOLS; c++) { e[c] = __expf(logits[NOPS + c] - mx); se += e[c]; }
            for (int c = 0; c < NCOLS; c++) {
                float a = e[c] / se;
                acol_s[c] = a;
                ws[WS_ACOL + t * NCOLS + c] = a;
            }
        }
        __syncthreads();
        // h_hist update (all 256 rows, one per thread)
        {
            float s = mh[tid];
            const float* ah = ws + WS_AH + tid * NOPS;
            #pragma unroll
            for (int o = 0; o < NOPS; o++) s += ah[o] * aop_s[o];
            const float* bh = ws + WS_BH + tid * NCOLS;
            #pragma unroll
            for (int c = 0; c < NCOLS; c++) s += bh[c] * acol_s[c];
            float hv = fast_tanh(s);
            __syncthreads();
            hH[tid] = hv;
        }
        __syncthreads();
    }
}

// ============================================================================
// Kernel C: fused table pass, 4 lanes per row (cq = tid&3 owns cols 4cq..4cq+3).
// Loads and stores are contiguous: address = const + tid*16B. Cross-lane
// sums via 2 shfl_xor. rs recursion duplicated in the 4 lanes (exact), block
// partials scaled by 0.25 to undo the duplication.
// ============================================================================
__global__ __launch_bounds__(256) void table_kernel(
        const float* __restrict__ table,
        const float* __restrict__ wsc,
        float* __restrict__ wspart,
        float* __restrict__ out,
        int rows) {
    const int tid = threadIdx.x;
    const int cq = tid & 3;
    const float lpiv = wsc[WS_LPIV];
    const float gpiv = wsc[WS_GPIV];
    float4 acol4[TSTEPS];
    float wg[TSTEPS], wl[TSTEPS], wand[TSTEPS], wor[TSTEPS], wrst[TSTEPS], wpass[TSTEPS];
    #pragma unroll
    for (int t = 0; t < TSTEPS; t++) {
        acol4[t] = make_float4(wsc[WS_ACOL + t * NCOLS + cq * 4 + 0],
                               wsc[WS_ACOL + t * NCOLS + cq * 4 + 1],
                               wsc[WS_ACOL + t * NCOLS + cq * 4 + 2],
                               wsc[WS_ACOL + t * NCOLS + cq * 4 + 3]);
        wg[t]   = wsc[WS_AOP + t * NOPS + 3];
        wl[t]   = wsc[WS_AOP + t * NOPS + 4];
        wand[t] = wsc[WS_AOP + t * NOPS + 5];
        wor[t]  = wsc[WS_AOP + t * NOPS + 6];
        wrst[t] = wsc[WS_AOP + t * NOPS + 8];
        wpass[t] = wsc[WS_AOP + t * NOPS + 0] + wsc[WS_AOP + t * NOPS + 1]
                 + wsc[WS_AOP + t * NOPS + 2] + wsc[WS_AOP + t * NOPS + 7];
    }
    const float wassign = wsc[WS_AOP + 3 * NOPS + 7];

    float dAcc[TSTEPS] = {0.f, 0.f, 0.f, 0.f};
    float nAcc[TSTEPS] = {0.f, 0.f, 0.f, 0.f};
    const long rowsL = rows;

    for (long r0 = (long)blockIdx.x * 64; r0 < rowsL; r0 += (long)NBLK_C * 64) {
        long row = r0 + (tid >> 2);
        bool valid = row < rowsL;
        float4 tv = valid ? *(const float4*)(table + row * NCOLS + cq * 4)
                          : make_float4(0.f, 0.f, 0.f, 0.f);
        float prs = tv.x + tv.y + tv.z + tv.w;
        float pg[4], pl[4];
        {
            float c0 = tv.x, c1 = tv.y, c2 = tv.z, c3 = tv.w;
            float sg0 = __builtin_amdgcn_rcpf(1.f + __expf(gpiv - c0));
            float sg1 = __builtin_amdgcn_rcpf(1.f + __expf(gpiv - c1));
            float sg2 = __builtin_amdgcn_rcpf(1.f + __expf(gpiv - c2));
            float sg3 = __builtin_amdgcn_rcpf(1.f + __expf(gpiv - c3));
            float sl0 = __builtin_amdgcn_rcpf(1.f + __expf(c0 - lpiv));
            float sl1 = __builtin_amdgcn_rcpf(1.f + __expf(c1 - lpiv));
            float sl2 = __builtin_amdgcn_rcpf(1.f + __expf(c2 - lpiv));
            float sl3 = __builtin_amdgcn_rcpf(1.f + __expf(c3 - lpiv));
            #pragma unroll
            for (int t = 0; t < TSTEPS; t++) {
                pg[t] = sg0 * acol4[t].x + sg1 * acol4[t].y + sg2 * acol4[t].z + sg3 * acol4[t].w;
                pl[t] = sl0 * acol4[t].x + sl1 * acol4[t].y + sl2 * acol4[t].z + sl3 * acol4[t].w;
            }
        }
        // reduce over the 4 lanes of this row (lanes differ in low 2 bits)
        prs += __shfl_xor(prs, 1); prs += __shfl_xor(prs, 2);
        #pragma unroll
        for (int t = 0; t < TSTEPS; t++) {
            pg[t] += __shfl_xor(pg[t], 1); pg[t] += __shfl_xor(pg[t], 2);
            pl[t] += __shfl_xor(pl[t], 1); pl[t] += __shfl_xor(pl[t], 2);
        }
        float rs1 = 1.f, rs2 = 1.f;
        float vf = valid ? 1.f : 0.f;
        #pragma unroll
        for (int i = 0; i < TSTEPS; i++) {
            dAcc[i] += vf * rs1 * prs;
            nAcc[i] += vf * rs1;
            float nrs = wg[i] * pg[i] + wl[i] * pl[i]
                      + wand[i] * fminf(rs1, rs2) + wor[i] * fmaxf(rs1, rs2)
                      + wrst[i] + wpass[i] * rs1;
            rs2 = rs1;
            rs1 = nrs;
        }
        if (valid) {
            float wa = wassign * rs1;   // rs^(4)
            f32x4u v = {wa * acol4[3].x, wa * acol4[3].y, wa * acol4[3].z, wa * acol4[3].w};
            *(f32x4u*)(out + 1 + row * NCOLS + cq * 4) = v;
        }
    }

    // block reduction of 8 partials (each row counted 4x -> scale 0.25)
    #pragma unroll
    for (int i = 0; i < TSTEPS; i++) {
        #pragma unroll
        for (int off = 32; off >= 1; off >>= 1) {
            dAcc[i] += __shfl_xor(dAcc[i], off);
            nAcc[i] += __shfl_xor(nAcc[i], off);
        }
    }
    __shared__ float redl[4][8];
    int wv = tid >> 6, ln = tid & 63;
    if (ln == 0) {
        #pragma unroll
        for (int i = 0; i < TSTEPS; i++) {
            redl[wv][i] = dAcc[i];
            redl[wv][4 + i] = nAcc[i];
        }
    }
    __syncthreads();
    if (tid < 8) {
        float s = redl[0][tid] + redl[1][tid] + redl[2][tid] + redl[3][tid];
        wspart[blockIdx.x * 8 + tid] = 0.25f * s;
    }
}

// ============================================================================
// Kernel D: reduce block partials, run the 4-step scalar recurrence
// ============================================================================
__global__ void finalize_kernel(const float* __restrict__ ws, float* __restrict__ out) {
    __shared__ float red[8];
    int a = threadIdx.x >> 5, l = threadIdx.x & 31;
    float s = 0.f;
    for (int b = l; b < NBLK_C; b += 32) s += ws[WS_PART + b * 8 + a];
    s += __shfl_xor(s, 1, 32); s += __shfl_xor(s, 2, 32); s += __shfl_xor(s, 4, 32);
    s += __shfl_xor(s, 8, 32); s += __shfl_xor(s, 16, 32);
    if (l == 0) red[a] = s;
    __syncthreads();
    if (threadIdx.x == 0) {
        float Dv[4] = {red[0], red[1], red[2], red[3]};
        float Nv[4] = {red[4], red[5], red[6], red[7]};
        const float* aop = ws + WS_AOP;
        float sc[5];
        sc[0] = 0.f;
        #pragma unroll
        for (int i = 0; i < 4; i++) {
            float s1 = sc[i];
            float s3 = sc[(i >= 2) ? (i - 2) : 0];
            sc[i + 1] = aop[i * NOPS + 0] * Dv[i] + aop[i * NOPS + 1] * Nv[i]
                      + aop[i * NOPS + 2] * (s3 - s1);
        }
        out[0] = sc[4];
    }
}

// ============================================================================
extern "C" void kernel_launch(void* const* d_in, const int* in_sizes, int n_in,
                              void* d_out, int out_size, void* d_ws, size_t ws_size,
                              hipStream_t stream) {
    const int*   q       = (const int*)d_in[0];
    const int*   nums    = (const int*)d_in[1];
    const int*   lwi     = (const int*)d_in[2];
    const float* table   = (const float*)d_in[3];
    const float* emb     = (const float*)d_in[4];
    const float* Wx      = (const float*)d_in[5];
    const float* Wh      = (const float*)d_in[6];
    const float* W_op    = (const float*)d_in[7];
    const float* op_emb  = (const float*)d_in[8];
    const float* W_col   = (const float*)d_in[9];
    const float* col_emb = (const float*)d_in[10];
    const float* W_hist  = (const float*)d_in[11];
    const float* U       = (const float*)d_in[12];
    float* out = (float*)d_out;
    float* ws  = (float*)d_ws;
    int rows = in_sizes[3] / NCOLS;

    const int pre_outputs = 137472;   // see precompute_kernel gid map
    precompute_kernel<<<(pre_outputs + 255) / 256, 256, 0, stream>>>(
        q, emb, Wx, Wh, W_op, W_col, W_hist, op_emb, col_emb, ws);
    rnn_kernel<<<1, 1024, 0, stream>>>(ws, lwi);
    qproj_kernel<<<64, 256, 0, stream>>>(W_op, W_col, ws);
    select_kernel<<<1, 256, 0, stream>>>(ws, U, nums, op_emb, col_emb);
    table_kernel<<<NBLK_C, 256, 0, stream>>>(
        table, ws, ws + WS_PART, out, rows);
    finalize_kernel<<<1, 256, 0, stream>>>(ws, out);
}

// Round 8
// 271.518 us; speedup vs baseline: 1.4982x; 1.1256x over previous
//
#include <hip/hip_runtime.h>
#include <hip/hip_fp16.h>
#include <math.h>

#define HDIM   256
#define QLEN   64
#define NNUM   8
#define NOPS   9
#define NCOLS  16
#define TSTEPS 4

// op indices: SUM=0 COUNT=1 DIFF=2 GREATER=3 LESSER=4 AND=5 OR=6 ASSIGN=7 RESET=8

// ---- workspace layout (float offsets) ----
#define WS_LPIV 0
#define WS_GPIV 1
#define WS_ACOL 2            // [4][16]
#define WS_AOP  66           // [4][9]
#define WS_Q    112          // [256] final question RNN state q
#define WS_PQO  368          // [256] W_op[:, :256] @ q
#define WS_PQC  624          // [256] W_col[:, :256] @ q
#define WS_HS   880          // [8][256] hidden states at left_word_indices
#define WS_XP   2928         // [64][256] xproj
#define WS_AH   19312        // [256][9]  W_hist[:, :256] @ op_emb.T
#define WS_BH   21616        // [256][16] W_hist[:, 256:512] @ col_emb.T
#define WS_WH16 25712        // Wh as f16, MFMA-fragment order (32768 halfs = 16384 f)
#define WS_M16  42096        // 3x 256x256 f16 (h-side of W_op/W_col/W_hist): 98304 floats
#define WS_PART 140400       // [NBLK_C][8] block partials (D0..3, N0..3)
#define NBLK_C  2048

typedef _Float16 f16x8 __attribute__((ext_vector_type(8)));
typedef _Float16 f16x4 __attribute__((ext_vector_type(4)));
typedef float    f32x4 __attribute__((ext_vector_type(4)));

__device__ __forceinline__ float fast_tanh(float x) {
    return 1.0f - 2.0f / (__expf(2.0f * x) + 1.0f);
}

// ============================================================================
// Kernel A: parallel precompute.
//  gid ranges:
//   [0, 16384)              xproj[t][j] = emb[q[t]] . Wx[j,:]
//   [16384, 18688)          AH[j][o]  = W_hist[j,0:256] . op_emb[o,:]
//   [18688, 22784)          BH[j][c]  = W_hist[j,256:512] . col_emb[c,:]
//   [22784, 39168)          Wh -> f16 fragment-order pack (dwords)
//   [39168, 137472)         W_op/W_col/W_hist h-side halves -> f16 pack
//                           (32768 dwords = 65536 halfs per matrix)
// ============================================================================
__global__ void precompute_kernel(const int* __restrict__ q,
                                  const float* __restrict__ emb,
                                  const float* __restrict__ Wx,
                                  const float* __restrict__ Wh,
                                  const float* __restrict__ W_op,
                                  const float* __restrict__ W_col,
                                  const float* __restrict__ W_hist,
                                  const float* __restrict__ op_emb,
                                  const float* __restrict__ col_emb,
                                  float* __restrict__ ws) {
    int gid = blockIdx.x * 256 + threadIdx.x;
    if (gid < QLEN * HDIM) {
        int t = gid >> 8, j = gid & 255;
        const float4* x4 = (const float4*)(emb + (size_t)q[t] * HDIM);
        const float4* w4 = (const float4*)(Wx + (size_t)j * HDIM);
        float s = 0.f;
        for (int k = 0; k < HDIM / 4; k++) {
            float4 a = x4[k], b = w4[k];
            s += a.x * b.x + a.y * b.y + a.z * b.z + a.w * b.w;
        }
        ws[WS_XP + t * HDIM + j] = s;
    } else if (gid < QLEN * HDIM + HDIM * NOPS) {
        int idx = gid - QLEN * HDIM;
        int j = idx / NOPS, o = idx % NOPS;
        const float4* w4 = (const float4*)(W_hist + (size_t)j * (3 * HDIM));
        const float4* e4 = (const float4*)(op_emb + (size_t)o * HDIM);
        float s = 0.f;
        for (int k = 0; k < HDIM / 4; k++) {
            float4 a = w4[k], b = e4[k];
            s += a.x * b.x + a.y * b.y + a.z * b.z + a.w * b.w;
        }
        ws[WS_AH + idx] = s;
    } else if (gid < QLEN * HDIM + HDIM * NOPS + HDIM * NCOLS) {
        int idx = gid - QLEN * HDIM - HDIM * NOPS;
        int j = idx / NCOLS, c = idx % NCOLS;
        const float4* w4 = (const float4*)(W_hist + (size_t)j * (3 * HDIM) + HDIM);
        const float4* e4 = (const float4*)(col_emb + (size_t)c * HDIM);
        float s = 0.f;
        for (int k = 0; k < HDIM / 4; k++) {
            float4 a = w4[k], b = e4[k];
            s += a.x * b.x + a.y * b.y + a.z * b.z + a.w * b.w;
        }
        ws[WS_BH + idx] = s;
    } else if (gid < 22784 + 16384) {
        // Wh f16 pack: half-index = (((W*8+kk)*4+quad)*16+qr)*8 + e,
        // value = Wh[16*W+qr][kk*32 + quad*8 + e]
        int did = gid - 22784;
        int hidx = did * 2;
        int e = hidx & 7, qr = (hidx >> 3) & 15, quad = (hidx >> 7) & 3;
        int kk = (hidx >> 9) & 7, w = hidx >> 12;
        const float* src = Wh + (size_t)(16 * w + qr) * HDIM + kk * 32 + quad * 8 + e;
        float2 v = *(const float2*)src;
        ((__half2*)(ws + WS_WH16))[did] = __floats2half2_rn(v.x, v.y);
    } else if (gid < 22784 + 16384 + 98304) {
        // M16 pack: mat m = did>>15 (32768 dwords = 65536 halfs per mat),
        // within-mat half-index = ((i)*256 + j)*8 + e  (i in [0,32)),
        // value = W_m[j][off_m + i*8 + e]
        int did = gid - (22784 + 16384);
        int mat = did >> 15;
        int hidx = (did & 32767) * 2;
        int e = hidx & 7, j = (hidx >> 3) & 255, i = hidx >> 11;
        const float* src;
        if (mat == 0)      src = W_op   + (size_t)j * (2 * HDIM) + HDIM     + i * 8 + e;
        else if (mat == 1) src = W_col  + (size_t)j * (2 * HDIM) + HDIM     + i * 8 + e;
        else               src = W_hist + (size_t)j * (3 * HDIM) + 2 * HDIM + i * 8 + e;
        float2 v = *(const float2*)src;
        ((__half2*)(ws + WS_M16))[did] = __floats2half2_rn(v.x, v.y);
    }
}

// ============================================================================
// Kernel B1: single block, 256 threads (4 waves) — question RNN.
// Wave w owns rows [64w,64w+64) as 4 MFMA tiles. A-fragments are loaded once
// and PINNED into VGPRs with an empty inline-asm barrier (defeats the
// allocator's rematerialize-from-L2 heuristic that made r5 2x slower).
// The 8 B-fragments are read once per wave per step and reused by all 4
// tiles (32 LDS reads/step vs 128 in the 16-wave version).
// Cooperative epilogue: qr==0 lanes dump raw accumulators to LDS; after a
// barrier each of the 256 threads does ONE tanh for its row (kills the 16x
// replicated epilogue VALU work that dominated r6's step time).
// ============================================================================
__global__ __launch_bounds__(256, 1) void rnn_kernel(
        float* __restrict__ ws,
        const int* __restrict__ lwi) {
    __shared__ float xpL[QLEN * HDIM];      // 64 KB
    __shared__ _Float16 hF[2][HDIM];        // double-buffered h (f16 B source)
    __shared__ float preact[HDIM];          // raw matvec result (pre-activation)
    __shared__ float hsL[NNUM * HDIM];      // 8 KB
    __shared__ float hQ[HDIM];
    __shared__ unsigned stepmask[QLEN];     // bit i set iff lwi[i]==s

    const int tid = threadIdx.x;
    const int wave = tid >> 6, lane = tid & 63;
    const int quad = lane >> 4, qr = lane & 15;

    // stage xproj to LDS: 16384 floats = 4096 float4s, 16 per thread, coalesced
    #pragma unroll
    for (int i = 0; i < 16; i++) {
        int idx = (i * 256 + tid) * 4;
        *(float4*)(xpL + idx) = *(const float4*)(ws + WS_XP + idx);
    }
    if (tid < QLEN) {
        unsigned m = 0;
        #pragma unroll
        for (int i = 0; i < NNUM; i++) m |= (lwi[i] == tid) ? (1u << i) : 0u;
        stepmask[tid] = m;
    }
    // A fragments: 4 tiles x 8 k-blocks, pre-packed f16, coalesced reads
    const _Float16* wsh = (const _Float16*)(ws + WS_WH16);
    f16x8 aW[4][8];
    #pragma unroll
    for (int r = 0; r < 4; r++)
        #pragma unroll
        for (int kk = 0; kk < 8; kk++)
            aW[r][kk] = *(const f16x8*)(wsh + ((size_t)(((4 * wave + r) * 8 + kk) * 64 + lane)) * 8);
    // pin the fragments into VGPRs (blocks rematerialization)
    #pragma unroll
    for (int r = 0; r < 4; r++)
        #pragma unroll
        for (int kk = 0; kk < 8; kk++) {
            f32x4 t = __builtin_bit_cast(f32x4, aW[r][kk]);
            asm volatile("" : "+v"(t));
            aW[r][kk] = __builtin_bit_cast(f16x8, t);
        }
    hF[0][tid] = (_Float16)0.f;
    __syncthreads();

    for (int s = 0; s < QLEN; s++) {
        const _Float16* hb = hF[s & 1];
        f16x8 bfrag[8];
        #pragma unroll
        for (int kk = 0; kk < 8; kk++)
            bfrag[kk] = *(const f16x8*)(hb + kk * 32 + quad * 8);   // broadcast read
        f32x4 acc[4];
        #pragma unroll
        for (int r = 0; r < 4; r++) acc[r] = (f32x4){0.f, 0.f, 0.f, 0.f};
        #pragma unroll
        for (int kk = 0; kk < 8; kk++)
            #pragma unroll
            for (int r = 0; r < 4; r++)   // 4 independent 8-deep chains
                acc[r] = __builtin_amdgcn_mfma_f32_16x16x32_f16(aW[r][kk], bfrag[kk], acc[r], 0, 0, 0);
        if (qr == 0) {
            #pragma unroll
            for (int r = 0; r < 4; r++) {
                int rb = 64 * wave + 16 * r + quad * 4;
                *(f32x4*)(preact + rb) = acc[r];
            }
        }
        __syncthreads();
        // cooperative epilogue: one row per thread
        {
            float h = fast_tanh(preact[tid] + xpL[s * HDIM + tid]);
            hF[(s + 1) & 1][tid] = (_Float16)h;
            unsigned m = stepmask[s];
            while (m) {                      // almost always zero iterations
                int i = __builtin_ctz(m);
                hsL[i * HDIM + tid] = h;
                m &= m - 1;
            }
            if (s == QLEN - 1) hQ[tid] = h;
        }
        __syncthreads();
    }
    // write back hs_sel and q
    #pragma unroll
    for (int i = 0; i < NNUM; i++) ws[WS_HS + i * HDIM + tid] = hsL[i * HDIM + tid];
    ws[WS_Q + tid] = hQ[tid];
}

// ============================================================================
// Kernel P2: parallel q-projections — pq_op[j] = W_op[j,:256].q,
// pq_col[j] = W_col[j,:256].q.  512 dots x 32 lanes = 64 blocks x 256.
// ============================================================================
__global__ void qproj_kernel(const float* __restrict__ W_op,
                             const float* __restrict__ W_col,
                             float* __restrict__ ws) {
    int gid = blockIdx.x * 256 + threadIdx.x;
    int dot = gid >> 5, l = gid & 31;
    int mat = dot >> 8, j = dot & 255;
    const float* w = (mat ? W_col : W_op) + (size_t)j * (2 * HDIM) + l * 8;
    const float* qv = ws + WS_Q + l * 8;
    float4 a0 = *(const float4*)w,        a1 = *(const float4*)(w + 4);
    float4 b0 = *(const float4*)qv,       b1 = *(const float4*)(qv + 4);
    float s = a0.x * b0.x + a0.y * b0.y + a0.z * b0.z + a0.w * b0.w
            + a1.x * b1.x + a1.y * b1.y + a1.z * b1.z + a1.w * b1.w;
    s += __shfl_xor(s, 1); s += __shfl_xor(s, 2); s += __shfl_xor(s, 4);
    s += __shfl_xor(s, 8); s += __shfl_xor(s, 16);
    if (l == 0) ws[(mat ? WS_PQC : WS_PQO) + j] = s;
}

// ============================================================================
// Kernel B2: single block, 256 threads — pivots + selector chain (T=4).
// ============================================================================
__global__ __launch_bounds__(256) void select_kernel(
        float* __restrict__ ws,
        const float* __restrict__ U,
        const int* __restrict__ nums,
        const float* __restrict__ op_emb,
        const float* __restrict__ col_emb) {
    __shared__ float zu[16];
    __shared__ float hH[HDIM];
    __shared__ float top_op[HDIM], top_col[HDIM], mh[HDIM];
    __shared__ float logits[32];
    __shared__ float aop_s[NOPS], acol_s[NCOLS];

    const int tid = threadIdx.x;

    // ---- pivots: 16 dots (i in [0,8), u in {0,1}), 16 lanes each ----
    {
        int g = tid >> 4, l = tid & 15;
        int i = g >> 1, u = g & 1;
        const float* z = ws + WS_HS + i * HDIM + l * 16;
        const float* uu = U + u * HDIM + l * 16;
        float s = 0.f;
        #pragma unroll
        for (int k = 0; k < 4; k++) {
            float4 a = *(const float4*)(z + k * 4), b = *(const float4*)(uu + k * 4);
            s += a.x * b.x + a.y * b.y + a.z * b.z + a.w * b.w;
        }
        s += __shfl_xor(s, 1); s += __shfl_xor(s, 2);
        s += __shfl_xor(s, 4); s += __shfl_xor(s, 8);
        if (l == 0) zu[g] = s;
    }
    if (tid < HDIM) hH[tid] = 0.f;
    __syncthreads();
    if (tid == 0) {
        #pragma unroll
        for (int u = 0; u < 2; u++) {
            float mx = -1e30f;
            for (int i = 0; i < NNUM; i++) mx = fmaxf(mx, zu[i * 2 + u]);
            float se = 0.f, pv = 0.f;
            for (int i = 0; i < NNUM; i++) {
                float e = __expf(zu[i * 2 + u] - mx);
                se += e;
                pv += e * (float)nums[i];
            }
            ws[u] = pv / se;
        }
    }
    __syncthreads();

    const _Float16* wsm = (const _Float16*)(ws + WS_M16);
    const float pqo = ws[WS_PQO + tid];
    const float pqc = ws[WS_PQC + tid];

    for (int t = 0; t < TSTEPS; t++) {
        float so = 0.f, sc = 0.f, sh = 0.f;
        #pragma unroll
        for (int i = 0; i < 32; i++) {
            float4 h0 = *(const float4*)(hH + i * 8);
            float4 h1 = *(const float4*)(hH + i * 8 + 4);
            f16x8 a = *(const f16x8*)(wsm + ((size_t)(0 * 32 + i) * 256 + tid) * 8);
            f16x8 b = *(const f16x8*)(wsm + ((size_t)(1 * 32 + i) * 256 + tid) * 8);
            f16x8 c = *(const f16x8*)(wsm + ((size_t)(2 * 32 + i) * 256 + tid) * 8);
            so += (float)a[0]*h0.x + (float)a[1]*h0.y + (float)a[2]*h0.z + (float)a[3]*h0.w
                + (float)a[4]*h1.x + (float)a[5]*h1.y + (float)a[6]*h1.z + (float)a[7]*h1.w;
            sc += (float)b[0]*h0.x + (float)b[1]*h0.y + (float)b[2]*h0.z + (float)b[3]*h0.w
                + (float)b[4]*h1.x + (float)b[5]*h1.y + (float)b[6]*h1.z + (float)b[7]*h1.w;
            sh += (float)c[0]*h0.x + (float)c[1]*h0.y + (float)c[2]*h0.z + (float)c[3]*h0.w
                + (float)c[4]*h1.x + (float)c[5]*h1.y + (float)c[6]*h1.z + (float)c[7]*h1.w;
        }
        top_op[tid]  = fast_tanh(pqo + so);
        top_col[tid] = fast_tanh(pqc + sc);
        mh[tid] = sh;
        __syncthreads();

        // logits: 25 dots of 256, 32 lanes each, 8 groups per pass
        #pragma unroll
        for (int d0 = 0; d0 < 32; d0 += 8) {
            int d = d0 + (tid >> 5), l = tid & 31;
            if (d < 25) {
                float s = 0.f;
                if (d < NOPS) {
                    const float* e = op_emb + (size_t)d * HDIM;
                    #pragma unroll
                    for (int m = 0; m < 8; m++) s += e[l * 8 + m] * top_op[l * 8 + m];
                } else {
                    const float* e = col_emb + (size_t)(d - NOPS) * HDIM;
                    #pragma unroll
                    for (int m = 0; m < 8; m++) s += e[l * 8 + m] * top_col[l * 8 + m];
                }
                s += __shfl_xor(s, 1); s += __shfl_xor(s, 2); s += __shfl_xor(s, 4);
                s += __shfl_xor(s, 8); s += __shfl_xor(s, 16);
                if (l == 0) logits[d] = s;
            }
        }
        __syncthreads();
        if (tid == 0) {
            float mx = -1e30f;
            for (int o = 0; o < NOPS; o++) mx = fmaxf(mx, logits[o]);
            float se = 0.f, e[NOPS];
            for (int o = 0; o < NOPS; o++) { e[o] = __expf(logits[o] - mx); se += e[o]; }
            for (int o = 0; o < NOPS; o++) {
                float a = e[o] / se;
                aop_s[o] = a;
                ws[WS_AOP + t * NOPS + o] = a;
            }
        } else if (tid == 32) {
            float mx = -1e30f;
            for (int c = 0; c < NCOLS; c++) mx = fmaxf(mx, logits[NOPS + c]);
            float se = 0.f, e[NCOLS];
            for (int c = 0; c < NCOLS; c++) { e[c] = __expf(logits[NOPS + c] - mx); se += e[c]; }
            for (int c = 0; c < NCOLS; c++) {
                float a = e[c] / se;
                acol_s[c] = a;
                ws[WS_ACOL + t * NCOLS + c] = a;
            }
        }
        __syncthreads();
        // h_hist update (all 256 rows, one per thread)
        {
            float s = mh[tid];
            const float* ah = ws + WS_AH + tid * NOPS;
            #pragma unroll
            for (int o = 0; o < NOPS; o++) s += ah[o] * aop_s[o];
            const float* bh = ws + WS_BH + tid * NCOLS;
            #pragma unroll
            for (int c = 0; c < NCOLS; c++) s += bh[c] * acol_s[c];
            float hv = fast_tanh(s);
            __syncthreads();
            hH[tid] = hv;
        }
        __syncthreads();
    }
}

// ============================================================================
// Kernel C: fused table pass, 4 lanes per row (cq = tid&3 owns cols 4cq..4cq+3).
// Loads: nt dwordx4 (via ext_vector f32x4 — HIP float4 is rejected by the
// nontemporal builtins), contiguous. Stores: 4x nt dword (the out+1 offset
// makes 16-B vector stores straddle cache lines; dword stores stay aligned
// and lane-contiguous). Cross-lane sums via 2 shfl_xor; rs recursion
// duplicated in the 4 lanes (exact); block partials scaled by 0.25.
// ============================================================================
__global__ __launch_bounds__(256) void table_kernel(
        const float* __restrict__ table,
        const float* __restrict__ wsc,
        float* __restrict__ wspart,
        float* __restrict__ out,
        int rows) {
    const int tid = threadIdx.x;
    const int cq = tid & 3;
    const float lpiv = wsc[WS_LPIV];
    const float gpiv = wsc[WS_GPIV];
    float4 acol4[TSTEPS];
    float wg[TSTEPS], wl[TSTEPS], wand[TSTEPS], wor[TSTEPS], wrst[TSTEPS], wpass[TSTEPS];
    #pragma unroll
    for (int t = 0; t < TSTEPS; t++) {
        acol4[t] = make_float4(wsc[WS_ACOL + t * NCOLS + cq * 4 + 0],
                               wsc[WS_ACOL + t * NCOLS + cq * 4 + 1],
                               wsc[WS_ACOL + t * NCOLS + cq * 4 + 2],
                               wsc[WS_ACOL + t * NCOLS + cq * 4 + 3]);
        wg[t]   = wsc[WS_AOP + t * NOPS + 3];
        wl[t]   = wsc[WS_AOP + t * NOPS + 4];
        wand[t] = wsc[WS_AOP + t * NOPS + 5];
        wor[t]  = wsc[WS_AOP + t * NOPS + 6];
        wrst[t] = wsc[WS_AOP + t * NOPS + 8];
        wpass[t] = wsc[WS_AOP + t * NOPS + 0] + wsc[WS_AOP + t * NOPS + 1]
                 + wsc[WS_AOP + t * NOPS + 2] + wsc[WS_AOP + t * NOPS + 7];
    }
    const float wassign = wsc[WS_AOP + 3 * NOPS + 7];

    float dAcc[TSTEPS] = {0.f, 0.f, 0.f, 0.f};
    float nAcc[TSTEPS] = {0.f, 0.f, 0.f, 0.f};
    const long rowsL = rows;

    for (long r0 = (long)blockIdx.x * 64; r0 < rowsL; r0 += (long)NBLK_C * 64) {
        long row = r0 + (tid >> 2);
        bool valid = row < rowsL;
        f32x4 tv = {0.f, 0.f, 0.f, 0.f};
        if (valid)
            tv = __builtin_nontemporal_load((const f32x4*)(table + row * NCOLS + cq * 4));
        float prs = tv.x + tv.y + tv.z + tv.w;
        float pg[4], pl[4];
        {
            float c0 = tv.x, c1 = tv.y, c2 = tv.z, c3 = tv.w;
            float sg0 = __builtin_amdgcn_rcpf(1.f + __expf(gpiv - c0));
            float sg1 = __builtin_amdgcn_rcpf(1.f + __expf(gpiv - c1));
            float sg2 = __builtin_amdgcn_rcpf(1.f + __expf(gpiv - c2));
            float sg3 = __builtin_amdgcn_rcpf(1.f + __expf(gpiv - c3));
            float sl0 = __builtin_amdgcn_rcpf(1.f + __expf(c0 - lpiv));
            float sl1 = __builtin_amdgcn_rcpf(1.f + __expf(c1 - lpiv));
            float sl2 = __builtin_amdgcn_rcpf(1.f + __expf(c2 - lpiv));
            float sl3 = __builtin_amdgcn_rcpf(1.f + __expf(c3 - lpiv));
            #pragma unroll
            for (int t = 0; t < TSTEPS; t++) {
                pg[t] = sg0 * acol4[t].x + sg1 * acol4[t].y + sg2 * acol4[t].z + sg3 * acol4[t].w;
                pl[t] = sl0 * acol4[t].x + sl1 * acol4[t].y + sl2 * acol4[t].z + sl3 * acol4[t].w;
            }
        }
        // reduce over the 4 lanes of this row (lanes differ in low 2 bits)
        prs += __shfl_xor(prs, 1); prs += __shfl_xor(prs, 2);
        #pragma unroll
        for (int t = 0; t < TSTEPS; t++) {
            pg[t] += __shfl_xor(pg[t], 1); pg[t] += __shfl_xor(pg[t], 2);
            pl[t] += __shfl_xor(pl[t], 1); pl[t] += __shfl_xor(pl[t], 2);
        }
        float rs1 = 1.f, rs2 = 1.f;
        float vf = valid ? 1.f : 0.f;
        #pragma unroll
        for (int i = 0; i < TSTEPS; i++) {
            dAcc[i] += vf * rs1 * prs;
            nAcc[i] += vf * rs1;
            float nrs = wg[i] * pg[i] + wl[i] * pl[i]
                      + wand[i] * fminf(rs1, rs2) + wor[i] * fmaxf(rs1, rs2)
                      + wrst[i] + wpass[i] * rs1;
            rs2 = rs1;
            rs1 = nrs;
        }
        if (valid) {
            float wa = wassign * rs1;   // rs^(4)
            float* ob = out + 1 + row * NCOLS + cq * 4;
            __builtin_nontemporal_store(wa * acol4[3].x, ob + 0);
            __builtin_nontemporal_store(wa * acol4[3].y, ob + 1);
            __builtin_nontemporal_store(wa * acol4[3].z, ob + 2);
            __builtin_nontemporal_store(wa * acol4[3].w, ob + 3);
        }
    }

    // block reduction of 8 partials (each row counted 4x -> scale 0.25)
    #pragma unroll
    for (int i = 0; i < TSTEPS; i++) {
        #pragma unroll
        for (int off = 32; off >= 1; off >>= 1) {
            dAcc[i] += __shfl_xor(dAcc[i], off);
            nAcc[i] += __shfl_xor(nAcc[i], off);
        }
    }
    __shared__ float redl[4][8];
    int wv = tid >> 6, ln = tid & 63;
    if (ln == 0) {
        #pragma unroll
        for (int i = 0; i < TSTEPS; i++) {
            redl[wv][i] = dAcc[i];
            redl[wv][4 + i] = nAcc[i];
        }
    }
    __syncthreads();
    if (tid < 8) {
        float s = redl[0][tid] + redl[1][tid] + redl[2][tid] + redl[3][tid];
        wspart[blockIdx.x * 8 + tid] = 0.25f * s;
    }
}

// ============================================================================
// Kernel D: reduce block partials, run the 4-step scalar recurrence
// ============================================================================
__global__ void finalize_kernel(const float* __restrict__ ws, float* __restrict__ out) {
    __shared__ float red[8];
    int a = threadIdx.x >> 5, l = threadIdx.x & 31;
    float s = 0.f;
    for (int b = l; b < NBLK_C; b += 32) s += ws[WS_PART + b * 8 + a];
    s += __shfl_xor(s, 1, 32); s += __shfl_xor(s, 2, 32); s += __shfl_xor(s, 4, 32);
    s += __shfl_xor(s, 8, 32); s += __shfl_xor(s, 16, 32);
    if (l == 0) red[a] = s;
    __syncthreads();
    if (threadIdx.x == 0) {
        float Dv[4] = {red[0], red[1], red[2], red[3]};
        float Nv[4] = {red[4], red[5], red[6], red[7]};
        const float* aop = ws + WS_AOP;
        float sc[5];
        sc[0] = 0.f;
        #pragma unroll
        for (int i = 0; i < 4; i++) {
            float s1 = sc[i];
            float s3 = sc[(i >= 2) ? (i - 2) : 0];
            sc[i + 1] = aop[i * NOPS + 0] * Dv[i] + aop[i * NOPS + 1] * Nv[i]
                      + aop[i * NOPS + 2] * (s3 - s1);
        }
        out[0] = sc[4];
    }
}

// ============================================================================
extern "C" void kernel_launch(void* const* d_in, const int* in_sizes, int n_in,
                              void* d_out, int out_size, void* d_ws, size_t ws_size,
                              hipStream_t stream) {
    const int*   q       = (const int*)d_in[0];
    const int*   nums    = (const int*)d_in[1];
    const int*   lwi     = (const int*)d_in[2];
    const float* table   = (const float*)d_in[3];
    const float* emb     = (const float*)d_in[4];
    const float* Wx      = (const float*)d_in[5];
    const float* Wh      = (const float*)d_in[6];
    const float* W_op    = (const float*)d_in[7];
    const float* op_emb  = (const float*)d_in[8];
    const float* W_col   = (const float*)d_in[9];
    const float* col_emb = (const float*)d_in[10];
    const float* W_hist  = (const float*)d_in[11];
    const float* U       = (const float*)d_in[12];
    float* out = (float*)d_out;
    float* ws  = (float*)d_ws;
    int rows = in_sizes[3] / NCOLS;

    const int pre_outputs = 137472;   // see precompute_kernel gid map
    precompute_kernel<<<(pre_outputs + 255) / 256, 256, 0, stream>>>(
        q, emb, Wx, Wh, W_op, W_col, W_hist, op_emb, col_emb, ws);
    rnn_kernel<<<1, 256, 0, stream>>>(ws, lwi);
    qproj_kernel<<<64, 256, 0, stream>>>(W_op, W_col, ws);
    select_kernel<<<1, 256, 0, stream>>>(ws, U, nums, op_emb, col_emb);
    table_kernel<<<NBLK_C, 256, 0, stream>>>(
        table, ws, ws + WS_PART, out, rows);
    finalize_kernel<<<1, 256, 0, stream>>>(ws, out);
}